// Round 7
// baseline (101.972 us; speedup 1.0000x reference)
//
#include <hip/hip_runtime.h>

#define G 8192
#define IMG_W 512
#define IMG_H 512
#define TILE 16
#define NTX (IMG_W / TILE)  // 32
#define NTY (IMG_H / TILE)  // 32
#define NTILES (NTX * NTY)  // 1024
#define BLK 256
#define BLKB 64             // chunk kernel: 1 wave, 4 px/lane
#define NCHUNK 4
#define CAP 1024            // per-tile list capacity (avg ~190)
#define ALPHA_THRESH (1.0f/255.0f)
#define ALPHA_CAP 0.99f
#define TRANS_THRESH 1e-4f

// ws layout (bytes)
#define OFF_TBL   32768              // G * 64
#define OFF_LIST  (OFF_TBL + G*64)   // NTILES * CAP * 2
#define OFF_N     (OFF_LIST + NTILES*CAP*2)
#define OFF_PART  (OFF_N + NTILES*4) // NTILES * NCHUNK * 256 * 16

// -----------------------------------------------------------------------
// Kernel 0: per-gaussian 16x16-tile span (exact conservative cull,
// packed u32) PLUS a packed 64B record per gaussian:
//   f4[0]=(mx,my,0.5a,b)  f4[1]=(0.5c,op,cr,cg)  f4[2]=(cb,0,0,0)
// -----------------------------------------------------------------------
__global__ __launch_bounds__(BLK)
void range_kernel(const float* __restrict__ means2d,
                  const float* __restrict__ conics,
                  const float* __restrict__ colors,
                  const float* __restrict__ opac,
                  unsigned int* __restrict__ ranges,
                  float* __restrict__ tbl)
{
    int g = blockIdx.x * BLK + threadIdx.x;
    if (g >= G) return;
    float op = opac[g];
    float a  = conics[3*g], b = conics[3*g+1], c = conics[3*g+2];
    float mx = means2d[2*g], my = means2d[2*g+1];
    float cr = colors[3*g], cg = colors[3*g+1], cb = colors[3*g+2];

    float4* t4 = (float4*)(tbl + (g << 4));
    t4[0] = make_float4(mx, my, 0.5f * a, b);
    t4[1] = make_float4(0.5f * c, op, cr, cg);
    t4[2] = make_float4(cb, 0.0f, 0.0f, 0.0f);

    unsigned int packed = 0xFFu;          // default: culled
    if (op * 255.0f >= 1.0f) {
        float smax = __logf(op * 255.0f);
        float det = fmaxf(a * c - b * b, 1e-12f);
        float rx = sqrtf(fmaxf(2.0f * smax * c / det, 0.0f)) * 1.0001f + 0.01f;
        float ry = sqrtf(fmaxf(2.0f * smax * a / det, 0.0f)) * 1.0001f + 0.01f;
        int txmin = (int)ceilf ((mx - rx - 15.5f) * 0.0625f);
        int txmax = (int)floorf((mx + rx -  0.5f) * 0.0625f);
        int tymin = (int)ceilf ((my - ry - 15.5f) * 0.0625f);
        int tymax = (int)floorf((my + ry -  0.5f) * 0.0625f);
        if (!(txmax < 0 || txmin > NTX-1 || tymax < 0 || tymin > NTY-1 ||
              txmin > txmax || tymin > tymax)) {
            txmin = max(txmin, 0); txmax = min(txmax, NTX-1);
            tymin = max(tymin, 0); tymax = min(tymax, NTY-1);
            packed = (unsigned)txmin | ((unsigned)txmax << 8)
                   | ((unsigned)tymin << 16) | ((unsigned)tymax << 24);
        }
    }
    ranges[g] = packed;
}

__device__ __forceinline__ int hitp(unsigned p, unsigned btx, unsigned bty)
{
    return (btx >= (p & 0xffu)) & (btx <= ((p >> 8) & 0xffu)) &
           (bty >= ((p >> 16) & 0xffu)) & (bty <= (p >> 24));
}

// -----------------------------------------------------------------------
// Kernel 1 (one 256-thread block per 16x16 tile): phases 1+2 only.
//  Phase 1: barrier-free two-pass scan + ballot compaction (idx order).
//  Phase 2: rank sort, 32-bit float-bit keys, POSITION tiebreak.
//  Writes the sorted list + count to global for the chunk kernel.
// -----------------------------------------------------------------------
__global__ __launch_bounds__(BLK)
void sort_kernel(const unsigned int* __restrict__ ranges,
                 const float* __restrict__ depths,
                 unsigned short* __restrict__ lists,
                 int* __restrict__ tile_n)
{
    __shared__ __align__(16) unsigned short slist[CAP];
    __shared__ __align__(16) unsigned int fkeys[CAP + 8];
    __shared__ int woff[4];

    const int t = threadIdx.x;
    const int lane = t & 63, w = t >> 6;
    const unsigned btx = blockIdx.x, bty = blockIdx.y;
    const int tile = (int)bty * NTX + (int)btx;

    // ---- Phase 1, pass A: load + count (no barriers) ----
    const uint4* r4 = (const uint4*)ranges;
    const int wbase = w * (G / 4);            // 2048 gaussians per wave
    uint4 rv[8];
    #pragma unroll
    for (int i = 0; i < 8; ++i)
        rv[i] = r4[(wbase >> 2) + i * 64 + lane];

    int cnt = 0;
    #pragma unroll
    for (int i = 0; i < 8; ++i)
        cnt += hitp(rv[i].x, btx, bty) + hitp(rv[i].y, btx, bty)
             + hitp(rv[i].z, btx, bty) + hitp(rv[i].w, btx, bty);
    #pragma unroll
    for (int d = 1; d < 64; d <<= 1) cnt += __shfl_xor(cnt, d);
    if (lane == 0) woff[w] = cnt;
    __syncthreads();

    int offs = 0;
    for (int ww = 0; ww < w; ++ww) offs += woff[ww];
    const int N = min(woff[0] + woff[1] + woff[2] + woff[3], CAP);

    // ---- Phase 1, pass B: ballot compaction ----
    const unsigned long long lt = (1ull << lane) - 1ull;
    #pragma unroll
    for (int i = 0; i < 8; ++i) {
        int gbase = wbase + i * 256 + lane * 4;
        int h0 = hitp(rv[i].x, btx, bty), h1 = hitp(rv[i].y, btx, bty);
        int h2 = hitp(rv[i].z, btx, bty), h3 = hitp(rv[i].w, btx, bty);
        unsigned long long m0 = __ballot(h0), m1 = __ballot(h1);
        unsigned long long m2 = __ballot(h2), m3 = __ballot(h3);
        int pos = offs + __popcll(m0 & lt) + __popcll(m1 & lt)
                       + __popcll(m2 & lt) + __popcll(m3 & lt);
        if (h0) { if (pos < CAP) slist[pos] = (unsigned short)(gbase    ); pos++; }
        if (h1) { if (pos < CAP) slist[pos] = (unsigned short)(gbase + 1); pos++; }
        if (h2) { if (pos < CAP) slist[pos] = (unsigned short)(gbase + 2); pos++; }
        if (h3) { if (pos < CAP) slist[pos] = (unsigned short)(gbase + 3); pos++; }
        offs += __popcll(m0) + __popcll(m1) + __popcll(m2) + __popcll(m3);
    }
    __syncthreads();

    // ---- Phase 2: rank sort, 32-bit keys + position tiebreak ----
    unsigned short myidx[4]; unsigned int mykey[4]; int myr[4];
    #pragma unroll
    for (int m = 0; m < 4; ++m) {
        int i = t + m * BLK;
        if (i < N) {
            unsigned idx = slist[i];
            unsigned k = __float_as_uint(depths[idx]);   // depths > 0
            myidx[m] = (unsigned short)idx; mykey[m] = k; fkeys[i] = k;
        }
    }
    if (t < 8) fkeys[N + t] = 0xFFFFFFFFu;   // pad: never counts as "<"
    __syncthreads();

    const uint4* fk4 = (const uint4*)fkeys;
    const int nj4 = (N + 3) >> 2;
    #pragma unroll
    for (int m = 0; m < 4; ++m) {
        int i = t + m * BLK;
        if (i < N) {
            unsigned ke = mykey[m]; int r = 0;
            for (int j4 = 0; j4 < nj4; ++j4) {
                uint4 kv = fk4[j4]; int j = j4 << 2;
                r += (int)((kv.x < ke) | ((kv.x == ke) & (j     < i)));
                r += (int)((kv.y < ke) | ((kv.y == ke) & (j + 1 < i)));
                r += (int)((kv.z < ke) | ((kv.z == ke) & (j + 2 < i)));
                r += (int)((kv.w < ke) | ((kv.w == ke) & (j + 3 < i)));
            }
            myr[m] = r;
        }
    }
    __syncthreads();
    #pragma unroll
    for (int m = 0; m < 4; ++m) {
        int i = t + m * BLK;
        if (i < N) slist[myr[m]] = myidx[m];
    }
    __syncthreads();

    // ---- write sorted list + count ----
    for (int i = t; i < N; i += BLK) lists[tile * CAP + i] = slist[i];
    if (t == 0) tile_n[tile] = N;
}

// -----------------------------------------------------------------------
// Kernel 2 (one 64-thread SINGLE-WAVE block per (tile, depth-chunk)):
//  4096 blocks -> 16 waves/CU (fixes the occupancy collapse) while each
//  36B LDS broadcast feeds 4 pixels (DS-issue work ~0.25x of R0).
//  Lane l covers pixels (x=l&15, y=4*(l>>4)+{0..3}); dx, dx^2 shared.
//  Per-pixel expression tree identical to the validated version.
//  Outputs per-chunk partial (rgb, T) per pixel; associativity:
//  C = Cf + Tf*Cb, T = Tf*Tb (telescoping bounds boundary error <=1e-4).
// -----------------------------------------------------------------------
__global__ __launch_bounds__(BLKB)
void chunk_kernel(const unsigned short* __restrict__ lists,
                  const int* __restrict__ tile_n,
                  const float* __restrict__ tbl,
                  float4* __restrict__ partials)
{
    __shared__ float4 sq0[BLKB];   // mx, my, 0.5a, b
    __shared__ float4 sq1[BLKB];   // 0.5c, op, r, g
    __shared__ float  sq2[BLKB];   // blue

    const int bx = blockIdx.x;             // tile*NCHUNK + chunk
    const int tile = bx >> 2, chunk = bx & 3;
    const int l = threadIdx.x;             // one wave
    const int n = tile_n[tile];
    const int csz = (n + NCHUNK - 1) >> 2;
    const int cs = chunk * csz;
    const int ce = min(n, cs + csz);

    const int tx = tile & (NTX - 1), ty = tile >> 5;
    const float px  = (float)(tx * TILE + (l & 15)) + 0.5f;
    const int   y0  = (l >> 4) << 2;
    const float py0 = (float)(ty * TILE + y0) + 0.5f;
    const float py1 = py0 + 1.0f, py2 = py0 + 2.0f, py3 = py0 + 3.0f;

    float T0=1.f,T1=1.f,T2=1.f,T3=1.f;
    float ar0=0.f,ag0=0.f,ab0=0.f, ar1=0.f,ag1=0.f,ab1=0.f;
    float ar2=0.f,ag2=0.f,ab2=0.f, ar3=0.f,ag3=0.f,ab3=0.f;

    for (int base = cs; base < ce; base += BLKB) {
        int k = min(BLKB, ce - base);
        float4 v0 = make_float4(0.f,0.f,0.f,0.f);
        float4 v1 = make_float4(0.f,0.f,0.f,0.f);
        float  v2 = 0.f;
        if (l < k) {
            int idx = lists[tile * CAP + base + l];
            const float4* b = (const float4*)(tbl + (idx << 4));
            v0 = b[0]; v1 = b[1]; v2 = ((const float*)b)[8];
        }
        __syncthreads();                   // 1-wave barrier: cheap
        sq0[l] = v0; sq1[l] = v1; sq2[l] = v2;
        __syncthreads();

        int k4 = (k + 3) & ~3;             // padded slots are no-ops
        bool fin = false;
        for (int i = 0; i < k4; i += 4) {
            #pragma unroll
            for (int u = 0; u < 4; ++u) {
                float4 q0 = sq0[i + u];    // ds_read_b128 (broadcast)
                float4 q1 = sq1[i + u];    // ds_read_b128 (broadcast)
                float  bl = sq2[i + u];    // ds_read_b32
                float dx = px - q0.x;
                float dxdx = dx * dx;
                float dy0 = py0 - q0.y, dy1 = py1 - q0.y;
                float dy2 = py2 - q0.y, dy3 = py3 - q0.y;
                float sg0 = fmaf(q0.z, dxdx, fmaf(q1.x, dy0*dy0, q0.w*(dx*dy0)));
                float sg1 = fmaf(q0.z, dxdx, fmaf(q1.x, dy1*dy1, q0.w*(dx*dy1)));
                float sg2 = fmaf(q0.z, dxdx, fmaf(q1.x, dy2*dy2, q0.w*(dx*dy2)));
                float sg3 = fmaf(q0.z, dxdx, fmaf(q1.x, dy3*dy3, q0.w*(dx*dy3)));
                float al0 = q1.y * __expf(-sg0);
                float al1 = q1.y * __expf(-sg1);
                float al2 = q1.y * __expf(-sg2);
                float al3 = q1.y * __expf(-sg3);
                al0 = ((sg0 >= 0.f) && (al0 >= ALPHA_THRESH)) ? fminf(al0, ALPHA_CAP) : 0.f;
                al1 = ((sg1 >= 0.f) && (al1 >= ALPHA_THRESH)) ? fminf(al1, ALPHA_CAP) : 0.f;
                al2 = ((sg2 >= 0.f) && (al2 >= ALPHA_THRESH)) ? fminf(al2, ALPHA_CAP) : 0.f;
                al3 = ((sg3 >= 0.f) && (al3 >= ALPHA_THRESH)) ? fminf(al3, ALPHA_CAP) : 0.f;
                float w0 = al0*T0, w1 = al1*T1, w2 = al2*T2, w3 = al3*T3;
                ar0 = fmaf(w0, q1.z, ar0);  ar1 = fmaf(w1, q1.z, ar1);
                ar2 = fmaf(w2, q1.z, ar2);  ar3 = fmaf(w3, q1.z, ar3);
                ag0 = fmaf(w0, q1.w, ag0);  ag1 = fmaf(w1, q1.w, ag1);
                ag2 = fmaf(w2, q1.w, ag2);  ag3 = fmaf(w3, q1.w, ag3);
                ab0 = fmaf(w0, bl,   ab0);  ab1 = fmaf(w1, bl,   ab1);
                ab2 = fmaf(w2, bl,   ab2);  ab3 = fmaf(w3, bl,   ab3);
                T0 *= (1.f - al0);          // matches reference rounding
                T1 *= (1.f - al1);
                T2 *= (1.f - al2);
                T3 *= (1.f - al3);
            }
            // chunk-local deferred exit: remaining in-chunk terms sum to
            // <= localT < 1e-4 (x global prefix <= 1) -> within tolerance
            if (__all((T0 < TRANS_THRESH) & (T1 < TRANS_THRESH) &
                      (T2 < TRANS_THRESH) & (T3 < TRANS_THRESH))) {
                fin = true; break;
            }
        }
        if (fin) break;
    }

    float4* p = partials + ((long)bx << 8);   // 256 px per (tile,chunk)
    const int xl = l & 15;
    p[(y0    ) * 16 + xl] = make_float4(ar0, ag0, ab0, T0);
    p[(y0 + 1) * 16 + xl] = make_float4(ar1, ag1, ab1, T1);
    p[(y0 + 2) * 16 + xl] = make_float4(ar2, ag2, ab2, T2);
    p[(y0 + 3) * 16 + xl] = make_float4(ar3, ag3, ab3, T3);
}

// -----------------------------------------------------------------------
// Kernel 3: fold the 4 depth-chunk partials per pixel (back to front):
//   C = C0 + T0*(C1 + T1*(C2 + T2*C3))
// -----------------------------------------------------------------------
__global__ __launch_bounds__(BLK)
void merge_kernel(const float4* __restrict__ partials,
                  float* __restrict__ out)
{
    int px = blockIdx.x * BLK + threadIdx.x;     // 0 .. 262143
    int X = px & (IMG_W - 1), Y = px >> 9;
    int tile = (Y >> 4) * NTX + (X >> 4);
    int widx = (Y & 15) * 16 + (X & 15);
    const float4* base = partials + ((long)tile << 10);
    float4 p0 = base[widx];
    float4 p1 = base[256 + widx];
    float4 p2 = base[512 + widx];
    float4 p3 = base[768 + widx];
    float r = p3.x, g = p3.y, b = p3.z;
    r = fmaf(p2.w, r, p2.x); g = fmaf(p2.w, g, p2.y); b = fmaf(p2.w, b, p2.z);
    r = fmaf(p1.w, r, p1.x); g = fmaf(p1.w, g, p1.y); b = fmaf(p1.w, b, p1.z);
    r = fmaf(p0.w, r, p0.x); g = fmaf(p0.w, g, p0.y); b = fmaf(p0.w, b, p0.z);
    out[px*3]     = r;
    out[px*3 + 1] = g;
    out[px*3 + 2] = b;       // BG = 0 -> t_rem term vanishes
}

extern "C" void kernel_launch(void* const* d_in, const int* in_sizes, int n_in,
                              void* d_out, int out_size, void* d_ws, size_t ws_size,
                              hipStream_t stream)
{
    const float* means2d = (const float*)d_in[0];  // (G,2)
    const float* conics  = (const float*)d_in[1];  // (G,3)
    const float* colors  = (const float*)d_in[2];  // (G,3)
    const float* opac    = (const float*)d_in[3];  // (G,)
    const float* depths  = (const float*)d_in[4];  // (G,)
    float* out = (float*)d_out;

    unsigned int*   ranges   = (unsigned int*)d_ws;
    float*          tbl      = (float*)((char*)d_ws + OFF_TBL);
    unsigned short* lists    = (unsigned short*)((char*)d_ws + OFF_LIST);
    int*            tile_n   = (int*)((char*)d_ws + OFF_N);
    float4*         partials = (float4*)((char*)d_ws + OFF_PART);

    range_kernel<<<G / BLK, BLK, 0, stream>>>(means2d, conics, colors, opac,
                                              ranges, tbl);
    sort_kernel<<<dim3(NTX, NTY), BLK, 0, stream>>>(ranges, depths,
                                                    lists, tile_n);
    chunk_kernel<<<NTILES * NCHUNK, BLKB, 0, stream>>>(lists, tile_n,
                                                       tbl, partials);
    merge_kernel<<<(IMG_W * IMG_H) / BLK, BLK, 0, stream>>>(partials, out);
}

// Round 8
// 87.082 us; speedup vs baseline: 1.1710x; 1.1710x over previous
//
#include <hip/hip_runtime.h>

#define G 8192
#define IMG_W 512
#define IMG_H 512
#define TILE 16
#define NTX (IMG_W / TILE)  // 32
#define NTY (IMG_H / TILE)  // 32
#define BLK 256
#define BLKB 64             // per-wave chunk staging group
#define CAP 1024            // per-tile list capacity (avg ~190)
#define ALPHA_THRESH (1.0f/255.0f)
#define ALPHA_CAP 0.99f
#define TRANS_THRESH 1e-4f

// -----------------------------------------------------------------------
// Kernel 0: per-gaussian 16x16-tile span (exact conservative cull,
// packed u32) PLUS a packed 64B record per gaussian:
//   f4[0]=(mx,my,0.5a,b)  f4[1]=(0.5c,op,cr,cg)  f4[2]=(cb,0,0,0)
// -----------------------------------------------------------------------
__global__ __launch_bounds__(BLK)
void range_kernel(const float* __restrict__ means2d,
                  const float* __restrict__ conics,
                  const float* __restrict__ colors,
                  const float* __restrict__ opac,
                  unsigned int* __restrict__ ranges,
                  float* __restrict__ tbl)
{
    int g = blockIdx.x * BLK + threadIdx.x;
    if (g >= G) return;
    float op = opac[g];
    float a  = conics[3*g], b = conics[3*g+1], c = conics[3*g+2];
    float mx = means2d[2*g], my = means2d[2*g+1];
    float cr = colors[3*g], cg = colors[3*g+1], cb = colors[3*g+2];

    float4* t4 = (float4*)(tbl + (g << 4));
    t4[0] = make_float4(mx, my, 0.5f * a, b);
    t4[1] = make_float4(0.5f * c, op, cr, cg);
    t4[2] = make_float4(cb, 0.0f, 0.0f, 0.0f);

    unsigned int packed = 0xFFu;          // default: culled
    if (op * 255.0f >= 1.0f) {
        float smax = __logf(op * 255.0f);
        float det = fmaxf(a * c - b * b, 1e-12f);
        float rx = sqrtf(fmaxf(2.0f * smax * c / det, 0.0f)) * 1.0001f + 0.01f;
        float ry = sqrtf(fmaxf(2.0f * smax * a / det, 0.0f)) * 1.0001f + 0.01f;
        int txmin = (int)ceilf ((mx - rx - 15.5f) * 0.0625f);
        int txmax = (int)floorf((mx + rx -  0.5f) * 0.0625f);
        int tymin = (int)ceilf ((my - ry - 15.5f) * 0.0625f);
        int tymax = (int)floorf((my + ry -  0.5f) * 0.0625f);
        if (!(txmax < 0 || txmin > NTX-1 || tymax < 0 || tymin > NTY-1 ||
              txmin > txmax || tymin > tymax)) {
            txmin = max(txmin, 0); txmax = min(txmax, NTX-1);
            tymin = max(tymin, 0); tymax = min(tymax, NTY-1);
            packed = (unsigned)txmin | ((unsigned)txmax << 8)
                   | ((unsigned)tymin << 16) | ((unsigned)tymax << 24);
        }
    }
    ranges[g] = packed;
}

__device__ __forceinline__ int hitp(unsigned p, unsigned btx, unsigned bty)
{
    return (btx >= (p & 0xffu)) & (btx <= ((p >> 8) & 0xffu)) &
           (bty >= ((p >> 16) & 0xffu)) & (bty <= (p >> 24));
}

// -----------------------------------------------------------------------
// Kernel 1 (one 256-thread block per 16x16 tile; 4 waves):
//  Phase 1: barrier-free two-pass scan + ballot compaction (idx order).
//  Phase 2: rank sort, 32-bit float-bit keys, POSITION tiebreak.
//  Phase 3: CHUNKED composite — wave w composites depth-chunk w of the
//           sorted list over the WHOLE tile at 4 px/lane. Per-CU DS
//           broadcast issue drops 4x vs the classic layout (each 36B
//           broadcast feeds 4 px; each list entry read by 1 wave) while
//           keeping 16 waves/CU. Per-wave staging buffers; no barriers
//           in the composite loop (wave-internal DS ordering).
//  Phase 4: in-LDS fold C = C0+T0*(C1+T1*(C2+T2*C3)) (R7-validated
//           associativity; boundary masking error <= 1e-4 telescoped).
// -----------------------------------------------------------------------
__global__ __launch_bounds__(BLK)
void tile_kernel(const unsigned int* __restrict__ ranges,
                 const float* __restrict__ depths,
                 const float* __restrict__ tbl,
                 float*       __restrict__ out)
{
    __shared__ __align__(16) unsigned short slist[CAP];
    __shared__ __align__(16) unsigned int fkeys[CAP + 8];
    __shared__ int woff[4];
    __shared__ float4 sq0[4][BLKB];   // per-wave: mx, my, 0.5a, b
    __shared__ float4 sq1[4][BLKB];   // per-wave: 0.5c, op, r, g
    __shared__ float  sq2[4][BLKB];   // per-wave: blue
    __shared__ float4 part[4][BLK];   // per-wave partial (r,g,b,T) per px

    const int t = threadIdx.x;
    const int lane = t & 63, w = t >> 6;
    const unsigned btx = blockIdx.x, bty = blockIdx.y;

    // ---- Phase 1, pass A: load + count (no barriers) ----
    const uint4* r4 = (const uint4*)ranges;
    const int wbase = w * (G / 4);            // 2048 gaussians per wave
    uint4 rv[8];
    #pragma unroll
    for (int i = 0; i < 8; ++i)
        rv[i] = r4[(wbase >> 2) + i * 64 + lane];

    int cnt = 0;
    #pragma unroll
    for (int i = 0; i < 8; ++i)
        cnt += hitp(rv[i].x, btx, bty) + hitp(rv[i].y, btx, bty)
             + hitp(rv[i].z, btx, bty) + hitp(rv[i].w, btx, bty);
    #pragma unroll
    for (int d = 1; d < 64; d <<= 1) cnt += __shfl_xor(cnt, d);
    if (lane == 0) woff[w] = cnt;
    __syncthreads();

    int offs = 0;
    for (int ww = 0; ww < w; ++ww) offs += woff[ww];
    const int N = min(woff[0] + woff[1] + woff[2] + woff[3], CAP);

    // ---- Phase 1, pass B: ballot compaction ----
    const unsigned long long lt = (1ull << lane) - 1ull;
    #pragma unroll
    for (int i = 0; i < 8; ++i) {
        int gbase = wbase + i * 256 + lane * 4;
        int h0 = hitp(rv[i].x, btx, bty), h1 = hitp(rv[i].y, btx, bty);
        int h2 = hitp(rv[i].z, btx, bty), h3 = hitp(rv[i].w, btx, bty);
        unsigned long long m0 = __ballot(h0), m1 = __ballot(h1);
        unsigned long long m2 = __ballot(h2), m3 = __ballot(h3);
        int pos = offs + __popcll(m0 & lt) + __popcll(m1 & lt)
                       + __popcll(m2 & lt) + __popcll(m3 & lt);
        if (h0) { if (pos < CAP) slist[pos] = (unsigned short)(gbase    ); pos++; }
        if (h1) { if (pos < CAP) slist[pos] = (unsigned short)(gbase + 1); pos++; }
        if (h2) { if (pos < CAP) slist[pos] = (unsigned short)(gbase + 2); pos++; }
        if (h3) { if (pos < CAP) slist[pos] = (unsigned short)(gbase + 3); pos++; }
        offs += __popcll(m0) + __popcll(m1) + __popcll(m2) + __popcll(m3);
    }
    __syncthreads();

    // ---- Phase 2: rank sort, 32-bit keys + position tiebreak ----
    unsigned short myidx[4]; unsigned int mykey[4]; int myr[4];
    #pragma unroll
    for (int m = 0; m < 4; ++m) {
        int i = t + m * BLK;
        if (i < N) {
            unsigned idx = slist[i];
            unsigned k = __float_as_uint(depths[idx]);   // depths > 0
            myidx[m] = (unsigned short)idx; mykey[m] = k; fkeys[i] = k;
        }
    }
    if (t < 8) fkeys[N + t] = 0xFFFFFFFFu;   // pad: never counts as "<"
    __syncthreads();

    const uint4* fk4 = (const uint4*)fkeys;
    const int nj4 = (N + 3) >> 2;
    #pragma unroll
    for (int m = 0; m < 4; ++m) {
        int i = t + m * BLK;
        if (i < N) {
            unsigned ke = mykey[m]; int r = 0;
            for (int j4 = 0; j4 < nj4; ++j4) {
                uint4 kv = fk4[j4]; int j = j4 << 2;
                r += (int)((kv.x < ke) | ((kv.x == ke) & (j     < i)));
                r += (int)((kv.y < ke) | ((kv.y == ke) & (j + 1 < i)));
                r += (int)((kv.z < ke) | ((kv.z == ke) & (j + 2 < i)));
                r += (int)((kv.w < ke) | ((kv.w == ke) & (j + 3 < i)));
            }
            myr[m] = r;
        }
    }
    __syncthreads();
    #pragma unroll
    for (int m = 0; m < 4; ++m) {
        int i = t + m * BLK;
        if (i < N) slist[myr[m]] = myidx[m];
    }
    __syncthreads();

    // ---- Phase 3: wave w composites depth-chunk w, 4 px/lane ----
    // lane l covers pixels (x = l&15, y = 4*(l>>4) + {0..3})
    const int csz = (N + 3) >> 2;
    const int cs = w * csz;
    const int ce = min(N, cs + csz);

    const float px  = (float)(btx * TILE + (lane & 15)) + 0.5f;
    const int   y0  = (lane >> 4) << 2;
    const float py0 = (float)(bty * TILE + y0) + 0.5f;
    const float py1 = py0 + 1.0f, py2 = py0 + 2.0f, py3 = py0 + 3.0f;

    float T0=1.f,T1=1.f,T2=1.f,T3=1.f;
    float ar0=0.f,ag0=0.f,ab0=0.f, ar1=0.f,ag1=0.f,ab1=0.f;
    float ar2=0.f,ag2=0.f,ab2=0.f, ar3=0.f,ag3=0.f,ab3=0.f;

    for (int base = cs; base < ce; base += BLKB) {
        int k = min(BLKB, ce - base);
        // per-wave staging; pad slots are exact zero-gaussians (op=0)
        float4 v0 = make_float4(0.f,0.f,0.f,0.f);
        float4 v1 = make_float4(0.f,0.f,0.f,0.f);
        float  v2 = 0.f;
        if (lane < k) {
            int idx = slist[base + lane];
            const float4* b = (const float4*)(tbl + (idx << 4));
            v0 = b[0]; v1 = b[1]; v2 = ((const float*)b)[8];
        }
        sq0[w][lane] = v0; sq1[w][lane] = v1; sq2[w][lane] = v2;
        __threadfence_block();         // wave-internal LDS write->read order

        int k4 = (k + 3) & ~3;         // padded slots are no-ops
        bool fin = false;
        for (int i = 0; i < k4; i += 4) {
            #pragma unroll
            for (int u = 0; u < 4; ++u) {
                float4 q0 = sq0[w][i + u];   // ds_read_b128 (broadcast)
                float4 q1 = sq1[w][i + u];   // ds_read_b128 (broadcast)
                float  bl = sq2[w][i + u];   // ds_read_b32
                float dx = px - q0.x;
                float dxdx = dx * dx;
                float dy0 = py0 - q0.y, dy1 = py1 - q0.y;
                float dy2 = py2 - q0.y, dy3 = py3 - q0.y;
                float sg0 = fmaf(q0.z, dxdx, fmaf(q1.x, dy0*dy0, q0.w*(dx*dy0)));
                float sg1 = fmaf(q0.z, dxdx, fmaf(q1.x, dy1*dy1, q0.w*(dx*dy1)));
                float sg2 = fmaf(q0.z, dxdx, fmaf(q1.x, dy2*dy2, q0.w*(dx*dy2)));
                float sg3 = fmaf(q0.z, dxdx, fmaf(q1.x, dy3*dy3, q0.w*(dx*dy3)));
                float al0 = q1.y * __expf(-sg0);
                float al1 = q1.y * __expf(-sg1);
                float al2 = q1.y * __expf(-sg2);
                float al3 = q1.y * __expf(-sg3);
                al0 = ((sg0 >= 0.f) && (al0 >= ALPHA_THRESH)) ? fminf(al0, ALPHA_CAP) : 0.f;
                al1 = ((sg1 >= 0.f) && (al1 >= ALPHA_THRESH)) ? fminf(al1, ALPHA_CAP) : 0.f;
                al2 = ((sg2 >= 0.f) && (al2 >= ALPHA_THRESH)) ? fminf(al2, ALPHA_CAP) : 0.f;
                al3 = ((sg3 >= 0.f) && (al3 >= ALPHA_THRESH)) ? fminf(al3, ALPHA_CAP) : 0.f;
                float w0 = al0*T0, w1 = al1*T1, w2 = al2*T2, w3 = al3*T3;
                ar0 = fmaf(w0, q1.z, ar0);  ar1 = fmaf(w1, q1.z, ar1);
                ar2 = fmaf(w2, q1.z, ar2);  ar3 = fmaf(w3, q1.z, ar3);
                ag0 = fmaf(w0, q1.w, ag0);  ag1 = fmaf(w1, q1.w, ag1);
                ag2 = fmaf(w2, q1.w, ag2);  ag3 = fmaf(w3, q1.w, ag3);
                ab0 = fmaf(w0, bl,   ab0);  ab1 = fmaf(w1, bl,   ab1);
                ab2 = fmaf(w2, bl,   ab2);  ab3 = fmaf(w3, bl,   ab3);
                T0 *= (1.f - al0);           // matches reference rounding
                T1 *= (1.f - al1);
                T2 *= (1.f - al2);
                T3 *= (1.f - al3);
            }
            // chunk-local deferred exit (R7-validated): remaining in-chunk
            // terms telescope to <= localT < 1e-4 -> within tolerance
            if (__all((T0 < TRANS_THRESH) & (T1 < TRANS_THRESH) &
                      (T2 < TRANS_THRESH) & (T3 < TRANS_THRESH))) {
                fin = true; break;
            }
        }
        if (fin) break;
    }

    // ---- Phase 4: stash partials, fold front-to-back, write out ----
    {
        const int xl = lane & 15;
        part[w][(y0    ) * 16 + xl] = make_float4(ar0, ag0, ab0, T0);
        part[w][(y0 + 1) * 16 + xl] = make_float4(ar1, ag1, ab1, T1);
        part[w][(y0 + 2) * 16 + xl] = make_float4(ar2, ag2, ab2, T2);
        part[w][(y0 + 3) * 16 + xl] = make_float4(ar3, ag3, ab3, T3);
    }
    __syncthreads();

    // thread t folds pixel t: C = C0 + T0*(C1 + T1*(C2 + T2*C3))
    float4 p0 = part[0][t], p1 = part[1][t], p2 = part[2][t], p3 = part[3][t];
    float r = p3.x, g = p3.y, b = p3.z;
    r = fmaf(p2.w, r, p2.x); g = fmaf(p2.w, g, p2.y); b = fmaf(p2.w, b, p2.z);
    r = fmaf(p1.w, r, p1.x); g = fmaf(p1.w, g, p1.y); b = fmaf(p1.w, b, p1.z);
    r = fmaf(p0.w, r, p0.x); g = fmaf(p0.w, g, p0.y); b = fmaf(p0.w, b, p0.z);

    const int X = (int)btx * TILE + (t & 15);
    const int Y = (int)bty * TILE + (t >> 4);
    const int o = (Y * IMG_W + X) * 3;
    out[o]     = r;
    out[o + 1] = g;
    out[o + 2] = b;          // BG = 0 -> t_rem term vanishes
}

extern "C" void kernel_launch(void* const* d_in, const int* in_sizes, int n_in,
                              void* d_out, int out_size, void* d_ws, size_t ws_size,
                              hipStream_t stream)
{
    const float* means2d = (const float*)d_in[0];  // (G,2)
    const float* conics  = (const float*)d_in[1];  // (G,3)
    const float* colors  = (const float*)d_in[2];  // (G,3)
    const float* opac    = (const float*)d_in[3];  // (G,)
    const float* depths  = (const float*)d_in[4];  // (G,)
    float* out = (float*)d_out;
    unsigned int* ranges = (unsigned int*)d_ws;                 // 32 KB
    float* tbl = (float*)((char*)d_ws + 32 * 1024);             // G*64 B

    range_kernel<<<G / BLK, BLK, 0, stream>>>(means2d, conics, colors, opac,
                                              ranges, tbl);
    tile_kernel<<<dim3(NTX, NTY), dim3(BLK), 0, stream>>>(
        ranges, depths, tbl, out);
}

// Round 9
// 86.622 us; speedup vs baseline: 1.1772x; 1.0053x over previous
//
#include <hip/hip_runtime.h>

#define G 8192
#define IMG_W 512
#define IMG_H 512
#define TILE 16
#define NTX (IMG_W / TILE)  // 32
#define NTY (IMG_H / TILE)  // 32
#define BLK 256
#define BLKB 64             // per-wave chunk staging group
#define CAP 1024            // per-tile list capacity (avg ~190)
#define ALPHA_THRESH (1.0f/255.0f)
#define ALPHA_CAP 0.99f
#define TRANS_THRESH 1e-4f

// -----------------------------------------------------------------------
// Kernel 0: per-gaussian 16x16-tile span (exact conservative cull,
// packed u32) PLUS a packed 64B record per gaussian:
//   f4[0]=(mx,my,0.5a,b)  f4[1]=(0.5c,op,cr,cg)  f4[2]=(cb,0,0,0)
// -----------------------------------------------------------------------
__global__ __launch_bounds__(BLK)
void range_kernel(const float* __restrict__ means2d,
                  const float* __restrict__ conics,
                  const float* __restrict__ colors,
                  const float* __restrict__ opac,
                  unsigned int* __restrict__ ranges,
                  float* __restrict__ tbl)
{
    int g = blockIdx.x * BLK + threadIdx.x;
    if (g >= G) return;
    float op = opac[g];
    float a  = conics[3*g], b = conics[3*g+1], c = conics[3*g+2];
    float mx = means2d[2*g], my = means2d[2*g+1];
    float cr = colors[3*g], cg = colors[3*g+1], cb = colors[3*g+2];

    float4* t4 = (float4*)(tbl + (g << 4));
    t4[0] = make_float4(mx, my, 0.5f * a, b);
    t4[1] = make_float4(0.5f * c, op, cr, cg);
    t4[2] = make_float4(cb, 0.0f, 0.0f, 0.0f);

    unsigned int packed = 0xFFu;          // default: culled
    if (op * 255.0f >= 1.0f) {
        float smax = __logf(op * 255.0f);
        float det = fmaxf(a * c - b * b, 1e-12f);
        float rx = sqrtf(fmaxf(2.0f * smax * c / det, 0.0f)) * 1.0001f + 0.01f;
        float ry = sqrtf(fmaxf(2.0f * smax * a / det, 0.0f)) * 1.0001f + 0.01f;
        int txmin = (int)ceilf ((mx - rx - 15.5f) * 0.0625f);
        int txmax = (int)floorf((mx + rx -  0.5f) * 0.0625f);
        int tymin = (int)ceilf ((my - ry - 15.5f) * 0.0625f);
        int tymax = (int)floorf((my + ry -  0.5f) * 0.0625f);
        if (!(txmax < 0 || txmin > NTX-1 || tymax < 0 || tymin > NTY-1 ||
              txmin > txmax || tymin > tymax)) {
            txmin = max(txmin, 0); txmax = min(txmax, NTX-1);
            tymin = max(tymin, 0); tymax = min(tymax, NTY-1);
            packed = (unsigned)txmin | ((unsigned)txmax << 8)
                   | ((unsigned)tymin << 16) | ((unsigned)tymax << 24);
        }
    }
    ranges[g] = packed;
}

__device__ __forceinline__ int hitp(unsigned p, unsigned btx, unsigned bty)
{
    return (btx >= (p & 0xffu)) & (btx <= ((p >> 8) & 0xffu)) &
           (bty >= ((p >> 16) & 0xffu)) & (bty <= (p >> 24));
}

// -----------------------------------------------------------------------
// Kernel 1 (one 256-thread block per 16x16 tile; 4 waves):
//  Phase 1: barrier-free two-pass scan + ballot compaction (idx order).
//  Phase 2: rank sort, 32-bit float-bit keys, POSITION tiebreak.
//  Phase 3: CHUNKED composite — wave w composites depth-chunk w of the
//           sorted list over the WHOLE tile at 4 px/lane. The inner loop
//           is BRANCHLESS (exit check only between <=64-entry staging
//           rounds): no conditional break between ds_reads and compute,
//           so the compiler can software-pipeline the LDS reads with
//           counted lgkmcnt instead of stalling every 4 gaussians.
//           Blue components read as one ds_read_b128 per 4 gaussians.
//           Deferred-exit error bound unchanged: sum of post-crossing
//           weights <= T_cross < 1e-4 regardless of how many extra
//           gaussians are processed.
//  Phase 4: in-LDS fold C = C0+T0*(C1+T1*(C2+T2*C3)) (R7/R8-validated).
// -----------------------------------------------------------------------
__global__ __launch_bounds__(BLK)
void tile_kernel(const unsigned int* __restrict__ ranges,
                 const float* __restrict__ depths,
                 const float* __restrict__ tbl,
                 float*       __restrict__ out)
{
    __shared__ __align__(16) unsigned short slist[CAP];
    __shared__ __align__(16) unsigned int fkeys[CAP + 8];
    __shared__ int woff[4];
    __shared__ __align__(16) float4 sq0[4][BLKB];  // per-wave: mx,my,.5a,b
    __shared__ __align__(16) float4 sq1[4][BLKB];  // per-wave: .5c,op,r,g
    __shared__ __align__(16) float  sq2[4][BLKB];  // per-wave: blue
    __shared__ float4 part[4][BLK];                // per-wave (r,g,b,T)/px

    const int t = threadIdx.x;
    const int lane = t & 63, w = t >> 6;
    const unsigned btx = blockIdx.x, bty = blockIdx.y;

    // ---- Phase 1, pass A: load + count (no barriers) ----
    const uint4* r4 = (const uint4*)ranges;
    const int wbase = w * (G / 4);            // 2048 gaussians per wave
    uint4 rv[8];
    #pragma unroll
    for (int i = 0; i < 8; ++i)
        rv[i] = r4[(wbase >> 2) + i * 64 + lane];

    int cnt = 0;
    #pragma unroll
    for (int i = 0; i < 8; ++i)
        cnt += hitp(rv[i].x, btx, bty) + hitp(rv[i].y, btx, bty)
             + hitp(rv[i].z, btx, bty) + hitp(rv[i].w, btx, bty);
    #pragma unroll
    for (int d = 1; d < 64; d <<= 1) cnt += __shfl_xor(cnt, d);
    if (lane == 0) woff[w] = cnt;
    __syncthreads();

    int offs = 0;
    for (int ww = 0; ww < w; ++ww) offs += woff[ww];
    const int N = min(woff[0] + woff[1] + woff[2] + woff[3], CAP);

    // ---- Phase 1, pass B: ballot compaction ----
    const unsigned long long lt = (1ull << lane) - 1ull;
    #pragma unroll
    for (int i = 0; i < 8; ++i) {
        int gbase = wbase + i * 256 + lane * 4;
        int h0 = hitp(rv[i].x, btx, bty), h1 = hitp(rv[i].y, btx, bty);
        int h2 = hitp(rv[i].z, btx, bty), h3 = hitp(rv[i].w, btx, bty);
        unsigned long long m0 = __ballot(h0), m1 = __ballot(h1);
        unsigned long long m2 = __ballot(h2), m3 = __ballot(h3);
        int pos = offs + __popcll(m0 & lt) + __popcll(m1 & lt)
                       + __popcll(m2 & lt) + __popcll(m3 & lt);
        if (h0) { if (pos < CAP) slist[pos] = (unsigned short)(gbase    ); pos++; }
        if (h1) { if (pos < CAP) slist[pos] = (unsigned short)(gbase + 1); pos++; }
        if (h2) { if (pos < CAP) slist[pos] = (unsigned short)(gbase + 2); pos++; }
        if (h3) { if (pos < CAP) slist[pos] = (unsigned short)(gbase + 3); pos++; }
        offs += __popcll(m0) + __popcll(m1) + __popcll(m2) + __popcll(m3);
    }
    __syncthreads();

    // ---- Phase 2: rank sort, 32-bit keys + position tiebreak ----
    unsigned short myidx[4]; unsigned int mykey[4]; int myr[4];
    #pragma unroll
    for (int m = 0; m < 4; ++m) {
        int i = t + m * BLK;
        if (i < N) {
            unsigned idx = slist[i];
            unsigned k = __float_as_uint(depths[idx]);   // depths > 0
            myidx[m] = (unsigned short)idx; mykey[m] = k; fkeys[i] = k;
        }
    }
    if (t < 8) fkeys[N + t] = 0xFFFFFFFFu;   // pad: never counts as "<"
    __syncthreads();

    const uint4* fk4 = (const uint4*)fkeys;
    const int nj4 = (N + 3) >> 2;
    #pragma unroll
    for (int m = 0; m < 4; ++m) {
        int i = t + m * BLK;
        if (i < N) {
            unsigned ke = mykey[m]; int r = 0;
            for (int j4 = 0; j4 < nj4; ++j4) {
                uint4 kv = fk4[j4]; int j = j4 << 2;
                r += (int)((kv.x < ke) | ((kv.x == ke) & (j     < i)));
                r += (int)((kv.y < ke) | ((kv.y == ke) & (j + 1 < i)));
                r += (int)((kv.z < ke) | ((kv.z == ke) & (j + 2 < i)));
                r += (int)((kv.w < ke) | ((kv.w == ke) & (j + 3 < i)));
            }
            myr[m] = r;
        }
    }
    __syncthreads();
    #pragma unroll
    for (int m = 0; m < 4; ++m) {
        int i = t + m * BLK;
        if (i < N) slist[myr[m]] = myidx[m];
    }
    __syncthreads();

    // ---- Phase 3: wave w composites depth-chunk w, 4 px/lane ----
    // lane l covers pixels (x = l&15, y = 4*(l>>4) + {0..3})
    const int csz = (N + 3) >> 2;
    const int cs = w * csz;
    const int ce = min(N, cs + csz);

    const float px  = (float)(btx * TILE + (lane & 15)) + 0.5f;
    const int   y0  = (lane >> 4) << 2;
    const float py0 = (float)(bty * TILE + y0) + 0.5f;
    const float py1 = py0 + 1.0f, py2 = py0 + 2.0f, py3 = py0 + 3.0f;

    float T0=1.f,T1=1.f,T2=1.f,T3=1.f;
    float ar0=0.f,ag0=0.f,ab0=0.f, ar1=0.f,ag1=0.f,ab1=0.f;
    float ar2=0.f,ag2=0.f,ab2=0.f, ar3=0.f,ag3=0.f,ab3=0.f;

    for (int base = cs; base < ce; base += BLKB) {
        int k = min(BLKB, ce - base);
        // per-wave staging; pad slots are exact zero-gaussians (op=0)
        float4 v0 = make_float4(0.f,0.f,0.f,0.f);
        float4 v1 = make_float4(0.f,0.f,0.f,0.f);
        float  v2 = 0.f;
        if (lane < k) {
            int idx = slist[base + lane];
            const float4* b = (const float4*)(tbl + (idx << 4));
            v0 = b[0]; v1 = b[1]; v2 = ((const float*)b)[8];
        }
        sq0[w][lane] = v0; sq1[w][lane] = v1; sq2[w][lane] = v2;
        __threadfence_block();         // wave-internal LDS write->read order

        // BRANCHLESS loop over the staging round: no exit checks inside,
        // so ds_reads for group i+4 can be scheduled under compute of i.
        int k4 = (k + 3) & ~3;         // padded slots are no-ops
        #pragma unroll 2
        for (int i = 0; i < k4; i += 4) {
            float4 blv = *(const float4*)&sq2[w][i];   // 4 blues, 1 b128
            #pragma unroll
            for (int u = 0; u < 4; ++u) {
                float4 q0 = sq0[w][i + u];   // ds_read_b128 (broadcast)
                float4 q1 = sq1[w][i + u];   // ds_read_b128 (broadcast)
                float  bl = (u == 0) ? blv.x : (u == 1) ? blv.y
                          : (u == 2) ? blv.z : blv.w;
                float dx = px - q0.x;
                float dxdx = dx * dx;
                float dy0 = py0 - q0.y, dy1 = py1 - q0.y;
                float dy2 = py2 - q0.y, dy3 = py3 - q0.y;
                float sg0 = fmaf(q0.z, dxdx, fmaf(q1.x, dy0*dy0, q0.w*(dx*dy0)));
                float sg1 = fmaf(q0.z, dxdx, fmaf(q1.x, dy1*dy1, q0.w*(dx*dy1)));
                float sg2 = fmaf(q0.z, dxdx, fmaf(q1.x, dy2*dy2, q0.w*(dx*dy2)));
                float sg3 = fmaf(q0.z, dxdx, fmaf(q1.x, dy3*dy3, q0.w*(dx*dy3)));
                float al0 = q1.y * __expf(-sg0);
                float al1 = q1.y * __expf(-sg1);
                float al2 = q1.y * __expf(-sg2);
                float al3 = q1.y * __expf(-sg3);
                al0 = ((sg0 >= 0.f) && (al0 >= ALPHA_THRESH)) ? fminf(al0, ALPHA_CAP) : 0.f;
                al1 = ((sg1 >= 0.f) && (al1 >= ALPHA_THRESH)) ? fminf(al1, ALPHA_CAP) : 0.f;
                al2 = ((sg2 >= 0.f) && (al2 >= ALPHA_THRESH)) ? fminf(al2, ALPHA_CAP) : 0.f;
                al3 = ((sg3 >= 0.f) && (al3 >= ALPHA_THRESH)) ? fminf(al3, ALPHA_CAP) : 0.f;
                float w0 = al0*T0, w1 = al1*T1, w2 = al2*T2, w3 = al3*T3;
                ar0 = fmaf(w0, q1.z, ar0);  ar1 = fmaf(w1, q1.z, ar1);
                ar2 = fmaf(w2, q1.z, ar2);  ar3 = fmaf(w3, q1.z, ar3);
                ag0 = fmaf(w0, q1.w, ag0);  ag1 = fmaf(w1, q1.w, ag1);
                ag2 = fmaf(w2, q1.w, ag2);  ag3 = fmaf(w3, q1.w, ag3);
                ab0 = fmaf(w0, bl,   ab0);  ab1 = fmaf(w1, bl,   ab1);
                ab2 = fmaf(w2, bl,   ab2);  ab3 = fmaf(w3, bl,   ab3);
                T0 *= (1.f - al0);           // matches reference rounding
                T1 *= (1.f - al1);
                T2 *= (1.f - al2);
                T3 *= (1.f - al3);
            }
        }
        // exit check once per staging round (error <= T_cross < 1e-4)
        if (__all((T0 < TRANS_THRESH) & (T1 < TRANS_THRESH) &
                  (T2 < TRANS_THRESH) & (T3 < TRANS_THRESH))) break;
    }

    // ---- Phase 4: stash partials, fold front-to-back, write out ----
    {
        const int xl = lane & 15;
        part[w][(y0    ) * 16 + xl] = make_float4(ar0, ag0, ab0, T0);
        part[w][(y0 + 1) * 16 + xl] = make_float4(ar1, ag1, ab1, T1);
        part[w][(y0 + 2) * 16 + xl] = make_float4(ar2, ag2, ab2, T2);
        part[w][(y0 + 3) * 16 + xl] = make_float4(ar3, ag3, ab3, T3);
    }
    __syncthreads();

    // thread t folds pixel t: C = C0 + T0*(C1 + T1*(C2 + T2*C3))
    float4 p0 = part[0][t], p1 = part[1][t], p2 = part[2][t], p3 = part[3][t];
    float r = p3.x, g = p3.y, b = p3.z;
    r = fmaf(p2.w, r, p2.x); g = fmaf(p2.w, g, p2.y); b = fmaf(p2.w, b, p2.z);
    r = fmaf(p1.w, r, p1.x); g = fmaf(p1.w, g, p1.y); b = fmaf(p1.w, b, p1.z);
    r = fmaf(p0.w, r, p0.x); g = fmaf(p0.w, g, p0.y); b = fmaf(p0.w, b, p0.z);

    const int X = (int)btx * TILE + (t & 15);
    const int Y = (int)bty * TILE + (t >> 4);
    const int o = (Y * IMG_W + X) * 3;
    out[o]     = r;
    out[o + 1] = g;
    out[o + 2] = b;          // BG = 0 -> t_rem term vanishes
}

extern "C" void kernel_launch(void* const* d_in, const int* in_sizes, int n_in,
                              void* d_out, int out_size, void* d_ws, size_t ws_size,
                              hipStream_t stream)
{
    const float* means2d = (const float*)d_in[0];  // (G,2)
    const float* conics  = (const float*)d_in[1];  // (G,3)
    const float* colors  = (const float*)d_in[2];  // (G,3)
    const float* opac    = (const float*)d_in[3];  // (G,)
    const float* depths  = (const float*)d_in[4];  // (G,)
    float* out = (float*)d_out;
    unsigned int* ranges = (unsigned int*)d_ws;                 // 32 KB
    float* tbl = (float*)((char*)d_ws + 32 * 1024);             // G*64 B

    range_kernel<<<G / BLK, BLK, 0, stream>>>(means2d, conics, colors, opac,
                                              ranges, tbl);
    tile_kernel<<<dim3(NTX, NTY), dim3(BLK), 0, stream>>>(
        ranges, depths, tbl, out);
}